// Round 3
// baseline (884.690 us; speedup 1.0000x reference)
//
#include <hip/hip_runtime.h>
#include <hip/hip_bf16.h>

typedef __bf16 bf16x8 __attribute__((ext_vector_type(8)));
typedef float floatx4 __attribute__((ext_vector_type(4)));

#define LDK 72    // 64-wide K tiles, +8 bf16 pad (144B rows, 16B-aligned)
#define LDD 136   // 128-wide tiles, +8 bf16 pad (272B rows)

__device__ __forceinline__ unsigned short f2bf(float f) {
  unsigned u = __float_as_uint(f);
  u += 0x7fffu + ((u >> 16) & 1u);   // RNE; inputs finite
  return (unsigned short)(u >> 16);
}

// ------------- convert+transpose: fp32 [R][Ccol] -> bf16 [Ccol][R] -------------
__global__ __launch_bounds__(256) void transpose_cvt(
    const float* __restrict__ in, unsigned short* __restrict__ out,
    int R, int Ccol) {
  __shared__ unsigned short tile[32][33];
  int c0 = blockIdx.x * 32, r0 = blockIdx.y * 32;
  int tx = threadIdx.x & 31, ty = threadIdx.x >> 5;  // 32 x 8
  #pragma unroll
  for (int i = 0; i < 32; i += 8)
    tile[ty + i][tx] = f2bf(in[(size_t)(r0 + ty + i) * Ccol + c0 + tx]);
  __syncthreads();
  #pragma unroll
  for (int i = 0; i < 32; i += 8)
    out[(size_t)(c0 + ty + i) * R + r0 + tx] = tile[tx][ty + i];
}

// ---- shared BT-GEMM mainloop: C[128x128] = A[m0..][K] * Bt[n0..][K]^T
// AF32: A is fp32 in global, converted to bf16 during LDS staging.
template <bool AF32>
__device__ __forceinline__ void gemm_tile_mainloop(
    const void* __restrict__ Ap, const unsigned short* __restrict__ Bt,
    int K, int m0, int n0,
    unsigned short* As, unsigned short* Bs, floatx4 acc[4][4]) {
  const int t = threadIdx.x;
  const int lane = t & 63, w = t >> 6;
  const int wm = w >> 1, wn = w & 1;
  const int l15 = lane & 15, l4 = lane >> 4;
  const floatx4 zf = {0.f, 0.f, 0.f, 0.f};
  #pragma unroll
  for (int mi = 0; mi < 4; mi++)
    #pragma unroll
    for (int ni = 0; ni < 4; ni++) acc[mi][ni] = zf;

  for (int k0 = 0; k0 < K; k0 += 64) {
    __syncthreads();
    #pragma unroll
    for (int i = 0; i < 4; i++) {           // A: 128 rows x 8 chunks of 8 elems
      int c = t + i * 256;
      int row = c >> 3, kc = (c & 7) * 8;
      if (AF32) {
        const float* A = (const float*)Ap;
        const float4* src = (const float4*)&A[(size_t)(m0 + row) * K + k0 + kc];
        float4 a0 = src[0], a1 = src[1];
        uint4 dst;
        dst.x = (unsigned)f2bf(a0.x) | ((unsigned)f2bf(a0.y) << 16);
        dst.y = (unsigned)f2bf(a0.z) | ((unsigned)f2bf(a0.w) << 16);
        dst.z = (unsigned)f2bf(a1.x) | ((unsigned)f2bf(a1.y) << 16);
        dst.w = (unsigned)f2bf(a1.z) | ((unsigned)f2bf(a1.w) << 16);
        *(uint4*)(&As[row * LDK + kc]) = dst;
      } else {
        const unsigned short* A = (const unsigned short*)Ap;
        *(uint4*)(&As[row * LDK + kc]) =
            *(const uint4*)(&A[(size_t)(m0 + row) * K + k0 + kc]);
      }
    }
    #pragma unroll
    for (int i = 0; i < 4; i++) {           // Bt (bf16): 128 rows x 8 chunks
      int c = t + i * 256;
      int row = c >> 3, kc = (c & 7) * 8;
      *(uint4*)(&Bs[row * LDK + kc]) =
          *(const uint4*)(&Bt[(size_t)(n0 + row) * K + k0 + kc]);
    }
    __syncthreads();
    #pragma unroll
    for (int kk = 0; kk < 2; kk++) {
      bf16x8 af[4], bfr[4];
      #pragma unroll
      for (int mi = 0; mi < 4; mi++)
        af[mi] = *(const bf16x8*)(&As[(wm * 64 + mi * 16 + l15) * LDK + kk * 32 + l4 * 8]);
      #pragma unroll
      for (int ni = 0; ni < 4; ni++)
        bfr[ni] = *(const bf16x8*)(&Bs[(wn * 64 + ni * 16 + l15) * LDK + kk * 32 + l4 * 8]);
      #pragma unroll
      for (int mi = 0; mi < 4; mi++)
        #pragma unroll
        for (int ni = 0; ni < 4; ni++)
          acc[mi][ni] = __builtin_amdgcn_mfma_f32_16x16x32_bf16(
              af[mi], bfr[ni], acc[mi][ni], 0, 0, 0);
    }
  }
}

// ---- GEMM1: qkv = x(fp32) @ w_qkvT(bf16) + b(fp32); Q,K [B,H,S,D] bf16, V^T [B,H,D,S] bf16
__global__ __launch_bounds__(256, 3) void gemm_qkv(
    const float* __restrict__ X, const unsigned short* __restrict__ WT,
    const float* __restrict__ bias,
    unsigned short* __restrict__ Qo, unsigned short* __restrict__ Ko,
    unsigned short* __restrict__ Vto) {
  __shared__ unsigned short As[128 * LDK];
  __shared__ unsigned short Bs[128 * LDK];
  int n0 = blockIdx.x * 128, m0 = blockIdx.y * 128;
  floatx4 acc[4][4];
  gemm_tile_mainloop<true>(X, WT, 2048, m0, n0, As, Bs, acc);

  const int t = threadIdx.x, lane = t & 63, w = t >> 6;
  const int wm = w >> 1, wn = w & 1;
  const int l15 = lane & 15, l4 = lane >> 4;
  int which = n0 >> 11;            // 0:Q 1:K 2:V  (2048-col boundaries)
  int h = (n0 & 2047) >> 7;        // one head per 128-col block
  int b = m0 >> 11;
  int s0 = m0 & 2047;
  float bv[4];
  #pragma unroll
  for (int ni = 0; ni < 4; ni++)
    bv[ni] = bias[n0 + wn * 64 + ni * 16 + l15];

  if (which < 2) {
    unsigned short* dst = (which == 0) ? Qo : Ko;
    size_t base = (size_t)(b * 16 + h) * 2048;
    #pragma unroll
    for (int mi = 0; mi < 4; mi++)
      #pragma unroll
      for (int ni = 0; ni < 4; ni++) {
        int d = wn * 64 + ni * 16 + l15;
        #pragma unroll
        for (int r = 0; r < 4; r++) {
          int srow = s0 + wm * 64 + mi * 16 + l4 * 4 + r;
          dst[(base + srow) * 128 + d] = f2bf(acc[mi][ni][r] + bv[ni]);
        }
      }
  } else {
    #pragma unroll
    for (int mi = 0; mi < 4; mi++)
      #pragma unroll
      for (int ni = 0; ni < 4; ni++) {
        int d = wn * 64 + ni * 16 + l15;
        int sr = s0 + wm * 64 + mi * 16 + l4 * 4;   // 4 consecutive s rows
        ushort4 v;
        v.x = f2bf(acc[mi][ni][0] + bv[ni]);
        v.y = f2bf(acc[mi][ni][1] + bv[ni]);
        v.z = f2bf(acc[mi][ni][2] + bv[ni]);
        v.w = f2bf(acc[mi][ni][3] + bv[ni]);
        *(ushort4*)(&Vto[((size_t)(b * 16 + h) * 128 + d) * 2048 + sr]) = v;
      }
  }
}

// ---- flash attention: Q,K [B,H,S,D], V^T [B,H,D,S] (bf16) -> Y [B,S,C] (bf16)
__global__ __launch_bounds__(256, 2) void attn(
    const unsigned short* __restrict__ Qg, const unsigned short* __restrict__ Kg,
    const unsigned short* __restrict__ Vtg, unsigned short* __restrict__ Yg) {
  const int S = 2048, Dh = 128;
  const float c1 = 0.08838834764831845f * 1.4426950408889634f;  // scale*log2e
  const float NEG_BIG = -3.0e38f;   // finite sentinel: no inf-inf NaN paths
  __shared__ unsigned short Ks[64 * LDD];    // K tile [sk=64][d=128]
  __shared__ unsigned short Vs[128 * LDK];   // V^T tile [d=128][sk=64]
  __shared__ __bf16 Ps[4 * 32 * LDK];        // per-wave P [32 q][64 sk]
  int qt = blockIdx.x & 15;
  int bh = blockIdx.x >> 4;
  int q0 = qt * 128;
  const int t = threadIdx.x, lane = t & 63, w = t >> 6;
  const int l15 = lane & 15, l4 = lane >> 4;
  __bf16* Pw = &Ps[w * 32 * LDK];
  const unsigned short* Qb = Qg + (size_t)bh * S * Dh;
  const unsigned short* Kb = Kg + (size_t)bh * S * Dh;
  const unsigned short* Vb = Vtg + (size_t)bh * Dh * S;
  int qrow_base = q0 + w * 32;               // this wave's 32 q rows

  bf16x8 qf[2][4];                            // Q frags held in registers
  #pragma unroll
  for (int mi = 0; mi < 2; mi++)
    #pragma unroll
    for (int kk = 0; kk < 4; kk++)
      qf[mi][kk] = *(const bf16x8*)(
          &Qb[(size_t)(qrow_base + mi * 16 + l15) * Dh + kk * 32 + l4 * 8]);

  const floatx4 zf = {0.f, 0.f, 0.f, 0.f};
  floatx4 accO[2][8];
  #pragma unroll
  for (int mi = 0; mi < 2; mi++)
    #pragma unroll
    for (int nd = 0; nd < 8; nd++) accO[mi][nd] = zf;
  float mst[2][4], lst[2][4];
  #pragma unroll
  for (int mi = 0; mi < 2; mi++)
    #pragma unroll
    for (int r = 0; r < 4; r++) { mst[mi][r] = NEG_BIG; lst[mi][r] = 0.f; }

  int ntiles = (q0 >> 6) + 2;
  for (int kt = 0; kt < ntiles; kt++) {
    int k0 = kt * 64;
    __syncthreads();
    #pragma unroll
    for (int i = 0; i < 4; i++) {            // stage K: 64 rows x 16 chunks
      int c = t + i * 256;
      int row = c >> 4, dc = (c & 15) * 8;
      *(uint4*)(&Ks[row * LDD + dc]) =
          *(const uint4*)(&Kb[(size_t)(k0 + row) * Dh + dc]);
    }
    #pragma unroll
    for (int i = 0; i < 4; i++) {            // stage V^T: 128 rows x 8 chunks
      int c = t + i * 256;
      int row = c >> 3, sc2 = (c & 7) * 8;
      *(uint4*)(&Vs[row * LDK + sc2]) =
          *(const uint4*)(&Vb[(size_t)row * S + k0 + sc2]);
    }
    __syncthreads();

    if (k0 <= qrow_base + 31) {              // wave-uniform causal skip
      floatx4 sc[2][4];
      #pragma unroll
      for (int mi = 0; mi < 2; mi++)
        #pragma unroll
        for (int ni = 0; ni < 4; ni++) sc[mi][ni] = zf;
      #pragma unroll
      for (int kk = 0; kk < 4; kk++) {       // QK^T over D=128
        bf16x8 kf[4];
        #pragma unroll
        for (int ni = 0; ni < 4; ni++)
          kf[ni] = *(const bf16x8*)(&Ks[(ni * 16 + l15) * LDD + kk * 32 + l4 * 8]);
        #pragma unroll
        for (int mi = 0; mi < 2; mi++)
          #pragma unroll
          for (int ni = 0; ni < 4; ni++)
            sc[mi][ni] = __builtin_amdgcn_mfma_f32_16x16x32_bf16(
                qf[mi][kk], kf[ni], sc[mi][ni], 0, 0, 0);
      }
      if (k0 + 63 > qrow_base) {             // only diagonal-adjacent tiles
        #pragma unroll
        for (int mi = 0; mi < 2; mi++)
          #pragma unroll
          for (int ni = 0; ni < 4; ni++)
            #pragma unroll
            for (int r = 0; r < 4; r++) {
              int row = qrow_base + mi * 16 + l4 * 4 + r;
              int col = k0 + ni * 16 + l15;
              if (col > row) sc[mi][ni][r] = NEG_BIG;
            }
      }
      // ---- online softmax (rows live in 16-lane clusters, 4 rows per reg slot)
      float mt[2][4];
      #pragma unroll
      for (int mi = 0; mi < 2; mi++)
        #pragma unroll
        for (int r = 0; r < 4; r++)
          mt[mi][r] = fmaxf(fmaxf(sc[mi][0][r], sc[mi][1][r]),
                            fmaxf(sc[mi][2][r], sc[mi][3][r]));
      #pragma unroll
      for (int off = 1; off < 16; off <<= 1)
        #pragma unroll
        for (int mi = 0; mi < 2; mi++)
          #pragma unroll
          for (int r = 0; r < 4; r++)
            mt[mi][r] = fmaxf(mt[mi][r], __shfl_xor(mt[mi][r], off, 64));
      float alpha[2][4], rs[2][4];
      #pragma unroll
      for (int mi = 0; mi < 2; mi++)
        #pragma unroll
        for (int r = 0; r < 4; r++) {
          float mnew = fmaxf(mst[mi][r], mt[mi][r]);
          alpha[mi][r] = exp2f((mst[mi][r] - mnew) * c1);
          mst[mi][r] = mnew;
          rs[mi][r] = 0.f;
        }
      #pragma unroll
      for (int mi = 0; mi < 2; mi++)
        #pragma unroll
        for (int ni = 0; ni < 4; ni++)
          #pragma unroll
          for (int r = 0; r < 4; r++) {
            float p = exp2f((sc[mi][ni][r] - mst[mi][r]) * c1);
            rs[mi][r] += p;
            Pw[(mi * 16 + l4 * 4 + r) * LDK + ni * 16 + l15] =
                __builtin_bit_cast(__bf16, f2bf(p));
          }
      #pragma unroll
      for (int off = 1; off < 16; off <<= 1)
        #pragma unroll
        for (int mi = 0; mi < 2; mi++)
          #pragma unroll
          for (int r = 0; r < 4; r++)
            rs[mi][r] += __shfl_xor(rs[mi][r], off, 64);
      #pragma unroll
      for (int mi = 0; mi < 2; mi++)
        #pragma unroll
        for (int r = 0; r < 4; r++)
          lst[mi][r] = lst[mi][r] * alpha[mi][r] + rs[mi][r];
      #pragma unroll
      for (int mi = 0; mi < 2; mi++)
        #pragma unroll
        for (int nd = 0; nd < 8; nd++)
          #pragma unroll
          for (int r = 0; r < 4; r++) accO[mi][nd][r] *= alpha[mi][r];
      // ---- PV: P (A-layout via LDS round-trip) x V^T tile
      #pragma unroll
      for (int kk = 0; kk < 2; kk++) {
        bf16x8 pf[2];
        #pragma unroll
        for (int mi = 0; mi < 2; mi++)
          pf[mi] = *(const bf16x8*)(&Pw[(mi * 16 + l15) * LDK + kk * 32 + l4 * 8]);
        #pragma unroll
        for (int nd = 0; nd < 8; nd++) {
          bf16x8 vf = *(const bf16x8*)(&Vs[(nd * 16 + l15) * LDK + kk * 32 + l4 * 8]);
          #pragma unroll
          for (int mi = 0; mi < 2; mi++)
            accO[mi][nd] = __builtin_amdgcn_mfma_f32_16x16x32_bf16(
                pf[mi], vf, accO[mi][nd], 0, 0, 0);
        }
      }
    }
  }
  // ---- epilogue: Y[b][s][h*128+d] = O / l  (bf16)
  int b = bh >> 4, h = bh & 15;
  #pragma unroll
  for (int mi = 0; mi < 2; mi++)
    #pragma unroll
    for (int r = 0; r < 4; r++) {
      float inv = 1.0f / lst[mi][r];
      int srow = qrow_base + mi * 16 + l4 * 4 + r;
      size_t rowbase = ((size_t)(b * 2048 + srow)) * 2048 + h * 128;
      #pragma unroll
      for (int nd = 0; nd < 8; nd++)
        Yg[rowbase + nd * 16 + l15] = f2bf(accO[mi][nd][r] * inv);
    }
}

// ---- GEMM2: out(fp32) = y(bf16) @ w_projT(bf16) + b_proj(fp32)
__global__ __launch_bounds__(256, 3) void gemm_proj(
    const unsigned short* __restrict__ Yin, const unsigned short* __restrict__ WT,
    const float* __restrict__ bias, float* __restrict__ Og) {
  __shared__ unsigned short As[128 * LDK];
  __shared__ unsigned short Bs[128 * LDK];
  int n0 = blockIdx.x * 128, m0 = blockIdx.y * 128;
  floatx4 acc[4][4];
  gemm_tile_mainloop<false>(Yin, WT, 2048, m0, n0, As, Bs, acc);

  const int t = threadIdx.x, lane = t & 63, w = t >> 6;
  const int wm = w >> 1, wn = w & 1;
  const int l15 = lane & 15, l4 = lane >> 4;
  float bv[4];
  #pragma unroll
  for (int ni = 0; ni < 4; ni++)
    bv[ni] = bias[n0 + wn * 64 + ni * 16 + l15];
  #pragma unroll
  for (int mi = 0; mi < 4; mi++)
    #pragma unroll
    for (int ni = 0; ni < 4; ni++)
      #pragma unroll
      for (int r = 0; r < 4; r++)
        Og[(size_t)(m0 + wm * 64 + mi * 16 + l4 * 4 + r) * 2048 +
           n0 + wn * 64 + ni * 16 + l15] = acc[mi][ni][r] + bv[ni];
}

extern "C" void kernel_launch(void* const* d_in, const int* in_sizes, int n_in,
                              void* d_out, int out_size, void* d_ws, size_t ws_size,
                              hipStream_t stream) {
  const float* x      = (const float*)d_in[0]; // [4,2048,2048] fp32
  const float* w_qkv  = (const float*)d_in[1]; // [2048,6144] fp32
  const float* b_qkv  = (const float*)d_in[2]; // [6144] fp32
  const float* w_proj = (const float*)d_in[3]; // [2048,2048] fp32
  const float* b_proj = (const float*)d_in[4]; // [2048] fp32
  float* out = (float*)d_out;                  // [4,2048,2048] fp32 (64 MiB)
  char* ws = (char*)d_ws;

  // d_out doubles as mid-pipeline scratch (fully overwritten by gemm_proj):
  //   Q bf16 [B,H,S,D] at d_out[0,32M), K bf16 at d_out[32M,64M)
  // ws (88 MiB peak):
  //   [0,32M):  Vt bf16 [B,H,D,S]
  //   [32,64M): Y  bf16 [B,S,C]
  //   [64,88M): WqT bf16 [6144,2048], later WpT bf16 [2048,2048] (lifetimes disjoint)
  unsigned short* Q   = (unsigned short*)d_out;
  unsigned short* Kt  = (unsigned short*)((char*)d_out + 33554432);
  unsigned short* Vt  = (unsigned short*)(ws);
  unsigned short* Y   = (unsigned short*)(ws + 33554432);
  unsigned short* WqT = (unsigned short*)(ws + 67108864);
  unsigned short* WpT = (unsigned short*)(ws + 67108864);

  transpose_cvt<<<dim3(192, 64), 256, 0, stream>>>(w_qkv, WqT, 2048, 6144);
  gemm_qkv<<<dim3(48, 64), 256, 0, stream>>>(x, WqT, b_qkv, Q, Kt, Vt);
  attn<<<dim3(1024), 256, 0, stream>>>(Q, Kt, Vt, Y);
  transpose_cvt<<<dim3(64, 64), 256, 0, stream>>>(w_proj, WpT, 2048, 2048);
  gemm_proj<<<dim3(16, 64), 256, 0, stream>>>(Y, WpT, b_proj, out);
}

// Round 4
// 728.227 us; speedup vs baseline: 1.2149x; 1.2149x over previous
//
#include <hip/hip_runtime.h>
#include <hip/hip_bf16.h>

typedef __bf16 bf16x8 __attribute__((ext_vector_type(8)));
typedef float floatx4 __attribute__((ext_vector_type(4)));

#define LDK 72    // 64-wide K tiles, +8 bf16 pad (144B rows, 16B-aligned)
#define LDD 136   // 128-wide tiles, +8 bf16 pad (272B rows)

__device__ __forceinline__ unsigned short f2bf(float f) {
  unsigned u = __float_as_uint(f);
  u += 0x7fffu + ((u >> 16) & 1u);   // RNE; inputs finite
  return (unsigned short)(u >> 16);
}

// ------------- convert+transpose: fp32 [R][Ccol] -> bf16 [Ccol][R] -------------
__global__ __launch_bounds__(256) void transpose_cvt(
    const float* __restrict__ in, unsigned short* __restrict__ out,
    int R, int Ccol) {
  __shared__ unsigned short tile[32][33];
  int c0 = blockIdx.x * 32, r0 = blockIdx.y * 32;
  int tx = threadIdx.x & 31, ty = threadIdx.x >> 5;  // 32 x 8
  #pragma unroll
  for (int i = 0; i < 32; i += 8)
    tile[ty + i][tx] = f2bf(in[(size_t)(r0 + ty + i) * Ccol + c0 + tx]);
  __syncthreads();
  #pragma unroll
  for (int i = 0; i < 32; i += 8)
    out[(size_t)(c0 + ty + i) * R + r0 + tx] = tile[tx][ty + i];
}

// ---- shared BT-GEMM mainloop: C[128x128] = A[m0..][K] * Bt[n0..][K]^T
// AF32: A is fp32 in global, converted to bf16 during LDS staging.
template <bool AF32>
__device__ __forceinline__ void gemm_tile_mainloop(
    const void* __restrict__ Ap, const unsigned short* __restrict__ Bt,
    int K, int m0, int n0,
    unsigned short* As, unsigned short* Bs, floatx4 acc[4][4]) {
  const int t = threadIdx.x;
  const int lane = t & 63, w = t >> 6;
  const int wm = w >> 1, wn = w & 1;
  const int l15 = lane & 15, l4 = lane >> 4;
  const floatx4 zf = {0.f, 0.f, 0.f, 0.f};
  #pragma unroll
  for (int mi = 0; mi < 4; mi++)
    #pragma unroll
    for (int ni = 0; ni < 4; ni++) acc[mi][ni] = zf;

  for (int k0 = 0; k0 < K; k0 += 64) {
    __syncthreads();
    #pragma unroll
    for (int i = 0; i < 4; i++) {           // A: 128 rows x 8 chunks of 8 elems
      int c = t + i * 256;
      int row = c >> 3, kc = (c & 7) * 8;
      if (AF32) {
        const float* A = (const float*)Ap;
        const float4* src = (const float4*)&A[(size_t)(m0 + row) * K + k0 + kc];
        float4 a0 = src[0], a1 = src[1];
        uint4 dst;
        dst.x = (unsigned)f2bf(a0.x) | ((unsigned)f2bf(a0.y) << 16);
        dst.y = (unsigned)f2bf(a0.z) | ((unsigned)f2bf(a0.w) << 16);
        dst.z = (unsigned)f2bf(a1.x) | ((unsigned)f2bf(a1.y) << 16);
        dst.w = (unsigned)f2bf(a1.z) | ((unsigned)f2bf(a1.w) << 16);
        *(uint4*)(&As[row * LDK + kc]) = dst;
      } else {
        const unsigned short* A = (const unsigned short*)Ap;
        *(uint4*)(&As[row * LDK + kc]) =
            *(const uint4*)(&A[(size_t)(m0 + row) * K + k0 + kc]);
      }
    }
    #pragma unroll
    for (int i = 0; i < 4; i++) {           // Bt (bf16): 128 rows x 8 chunks
      int c = t + i * 256;
      int row = c >> 3, kc = (c & 7) * 8;
      *(uint4*)(&Bs[row * LDK + kc]) =
          *(const uint4*)(&Bt[(size_t)(n0 + row) * K + k0 + kc]);
    }
    __syncthreads();
    #pragma unroll
    for (int kk = 0; kk < 2; kk++) {
      bf16x8 af[4], bfr[4];
      #pragma unroll
      for (int mi = 0; mi < 4; mi++)
        af[mi] = *(const bf16x8*)(&As[(wm * 64 + mi * 16 + l15) * LDK + kk * 32 + l4 * 8]);
      #pragma unroll
      for (int ni = 0; ni < 4; ni++)
        bfr[ni] = *(const bf16x8*)(&Bs[(wn * 64 + ni * 16 + l15) * LDK + kk * 32 + l4 * 8]);
      #pragma unroll
      for (int mi = 0; mi < 4; mi++)
        #pragma unroll
        for (int ni = 0; ni < 4; ni++)
          acc[mi][ni] = __builtin_amdgcn_mfma_f32_16x16x32_bf16(
              af[mi], bfr[ni], acc[mi][ni], 0, 0, 0);
    }
  }
}

// ---- GEMM1: qkv = x(fp32) @ w_qkvT(bf16) + b(fp32); Q,K [B,H,S,D] bf16, V^T [B,H,D,S] bf16
__global__ __launch_bounds__(256, 3) void gemm_qkv(
    const float* __restrict__ X, const unsigned short* __restrict__ WT,
    const float* __restrict__ bias,
    unsigned short* __restrict__ Qo, unsigned short* __restrict__ Ko,
    unsigned short* __restrict__ Vto) {
  __shared__ unsigned short As[128 * LDK];
  __shared__ unsigned short Bs[128 * LDK];
  int n0 = blockIdx.x * 128, m0 = blockIdx.y * 128;
  floatx4 acc[4][4];
  gemm_tile_mainloop<true>(X, WT, 2048, m0, n0, As, Bs, acc);

  const int t = threadIdx.x, lane = t & 63, w = t >> 6;
  const int wm = w >> 1, wn = w & 1;
  const int l15 = lane & 15, l4 = lane >> 4;
  int which = n0 >> 11;            // 0:Q 1:K 2:V  (2048-col boundaries)
  int h = (n0 & 2047) >> 7;        // one head per 128-col block
  int b = m0 >> 11;
  int s0 = m0 & 2047;
  float bv[4];
  #pragma unroll
  for (int ni = 0; ni < 4; ni++)
    bv[ni] = bias[n0 + wn * 64 + ni * 16 + l15];

  if (which < 2) {
    unsigned short* dst = (which == 0) ? Qo : Ko;
    size_t base = (size_t)(b * 16 + h) * 2048;
    #pragma unroll
    for (int mi = 0; mi < 4; mi++)
      #pragma unroll
      for (int ni = 0; ni < 4; ni++) {
        int d = wn * 64 + ni * 16 + l15;
        #pragma unroll
        for (int r = 0; r < 4; r++) {
          int srow = s0 + wm * 64 + mi * 16 + l4 * 4 + r;
          dst[(base + srow) * 128 + d] = f2bf(acc[mi][ni][r] + bv[ni]);
        }
      }
  } else {
    #pragma unroll
    for (int mi = 0; mi < 4; mi++)
      #pragma unroll
      for (int ni = 0; ni < 4; ni++) {
        int d = wn * 64 + ni * 16 + l15;
        int sr = s0 + wm * 64 + mi * 16 + l4 * 4;   // 4 consecutive s rows
        ushort4 v;
        v.x = f2bf(acc[mi][ni][0] + bv[ni]);
        v.y = f2bf(acc[mi][ni][1] + bv[ni]);
        v.z = f2bf(acc[mi][ni][2] + bv[ni]);
        v.w = f2bf(acc[mi][ni][3] + bv[ni]);
        *(ushort4*)(&Vto[((size_t)(b * 16 + h) * 128 + d) * 2048 + sr]) = v;
      }
  }
}

// ---- flash attention: Q,K [B,H,S,D], V^T [B,H,D,S] (bf16) -> Y [B,S,C] (bf16)
// 64-row q-tiles (16 rows/wave); block processes the balanced pair (31-qtp, qtp):
// uniform 33 k-tile iterations per block. P overlays the K LDS region (K dead
// after QK^T; extra unconditional barrier). LDS 35840 B -> 4 blocks/CU.
__global__ __launch_bounds__(256, 4) void attn(
    const unsigned short* __restrict__ Qg, const unsigned short* __restrict__ Kg,
    const unsigned short* __restrict__ Vtg, unsigned short* __restrict__ Yg) {
  const int S = 2048, Dh = 128;
  const float c1 = 0.08838834764831845f * 1.4426950408889634f;  // scale*log2e
  const float NEG_BIG = -3.0e38f;
  __shared__ __bf16 KsPs[64 * LDD];   // 17408 B: K tile [sk=64][d=128]; P overlay (4x 16x72 = 9216 B)
  __shared__ __bf16 Vs[128 * LDK];    // 18432 B: V^T tile [d=128][sk=64]
  int qtp = blockIdx.x & 15;
  int bh = blockIdx.x >> 4;
  const int t = threadIdx.x, lane = t & 63, w = t >> 6;
  const int l15 = lane & 15, l4 = lane >> 4;
  const unsigned short* Qb = Qg + (size_t)bh * S * Dh;
  const unsigned short* Kb = Kg + (size_t)bh * S * Dh;
  const unsigned short* Vb = Vtg + (size_t)bh * Dh * S;
  __bf16* Pw = &KsPs[w * 16 * LDK];   // per-wave P [16 q][64 sk], stride 72
  int b = bh >> 4, h = bh & 15;
  const floatx4 zf = {0.f, 0.f, 0.f, 0.f};

  #pragma unroll 1
  for (int half = 0; half < 2; half++) {
    int qt = half ? qtp : (31 - qtp);
    int q0 = qt * 64;
    int qrow_base = q0 + w * 16;
    bf16x8 qf[4];
    #pragma unroll
    for (int kk = 0; kk < 4; kk++)
      qf[kk] = *(const bf16x8*)(
          &Qb[(size_t)(qrow_base + l15) * Dh + kk * 32 + l4 * 8]);
    floatx4 accO[8];
    #pragma unroll
    for (int nd = 0; nd < 8; nd++) accO[nd] = zf;
    float mst[4], lst[4];
    #pragma unroll
    for (int r = 0; r < 4; r++) { mst[r] = NEG_BIG; lst[r] = 0.f; }

    int ntiles = qt + 1;          // 64-row q-tile needs k-tiles 0..qt
    #pragma unroll 1
    for (int kt = 0; kt < ntiles; kt++) {
      int k0 = kt * 64;
      __syncthreads();            // prior iter's K/V/P reads done
      #pragma unroll
      for (int i = 0; i < 4; i++) {     // stage K: 64 rows x 16 chunks
        int c = t + i * 256;
        *(uint4*)(&KsPs[(c >> 4) * LDD + (c & 15) * 8]) =
            *(const uint4*)(&Kb[(size_t)(k0 + (c >> 4)) * Dh + (c & 15) * 8]);
      }
      #pragma unroll
      for (int i = 0; i < 4; i++) {     // stage V^T: 128 rows x 8 chunks
        int c = t + i * 256;
        *(uint4*)(&Vs[(c >> 3) * LDK + (c & 7) * 8]) =
            *(const uint4*)(&Vb[(size_t)(c >> 3) * S + k0 + (c & 7) * 8]);
      }
      __syncthreads();

      floatx4 sc[4];
      #pragma unroll
      for (int ni = 0; ni < 4; ni++) sc[ni] = zf;
      #pragma unroll
      for (int kk = 0; kk < 4; kk++) {  // QK^T over D=128
        bf16x8 kf[4];
        #pragma unroll
        for (int ni = 0; ni < 4; ni++)
          kf[ni] = *(const bf16x8*)(&KsPs[(ni * 16 + l15) * LDD + kk * 32 + l4 * 8]);
        #pragma unroll
        for (int ni = 0; ni < 4; ni++)
          sc[ni] = __builtin_amdgcn_mfma_f32_16x16x32_bf16(qf[kk], kf[ni], sc[ni], 0, 0, 0);
      }
      __syncthreads();            // all K reads done -> P may overwrite KsPs

      if (kt == qt) {             // diagonal tile: causal mask
        #pragma unroll
        for (int ni = 0; ni < 4; ni++)
          #pragma unroll
          for (int r = 0; r < 4; r++)
            if (ni * 16 + l15 > w * 16 + l4 * 4 + r) sc[ni][r] = NEG_BIG;
      }
      // ---- online softmax (rows in 16-lane clusters, 4 rows per reg slot)
      float mt[4];
      #pragma unroll
      for (int r = 0; r < 4; r++)
        mt[r] = fmaxf(fmaxf(sc[0][r], sc[1][r]), fmaxf(sc[2][r], sc[3][r]));
      #pragma unroll
      for (int off = 1; off < 16; off <<= 1)
        #pragma unroll
        for (int r = 0; r < 4; r++)
          mt[r] = fmaxf(mt[r], __shfl_xor(mt[r], off, 64));
      float alpha[4], rs[4];
      #pragma unroll
      for (int r = 0; r < 4; r++) {
        float mnew = fmaxf(mst[r], mt[r]);
        alpha[r] = exp2f((mst[r] - mnew) * c1);
        mst[r] = mnew;
        rs[r] = 0.f;
      }
      #pragma unroll
      for (int ni = 0; ni < 4; ni++)
        #pragma unroll
        for (int r = 0; r < 4; r++) {
          float p = exp2f((sc[ni][r] - mst[r]) * c1);
          rs[r] += p;
          Pw[(l4 * 4 + r) * LDK + ni * 16 + l15] = __builtin_bit_cast(__bf16, f2bf(p));
        }
      #pragma unroll
      for (int off = 1; off < 16; off <<= 1)
        #pragma unroll
        for (int r = 0; r < 4; r++)
          rs[r] += __shfl_xor(rs[r], off, 64);
      #pragma unroll
      for (int r = 0; r < 4; r++)
        lst[r] = lst[r] * alpha[r] + rs[r];
      #pragma unroll
      for (int nd = 0; nd < 8; nd++)
        #pragma unroll
        for (int r = 0; r < 4; r++) accO[nd][r] *= alpha[r];
      // ---- PV: P (A-layout, same-wave LDS round-trip) x V^T tile
      #pragma unroll
      for (int kk = 0; kk < 2; kk++) {
        bf16x8 pf = *(const bf16x8*)(&Pw[l15 * LDK + kk * 32 + l4 * 8]);
        #pragma unroll
        for (int nd = 0; nd < 8; nd++) {
          bf16x8 vf = *(const bf16x8*)(&Vs[(nd * 16 + l15) * LDK + kk * 32 + l4 * 8]);
          accO[nd] = __builtin_amdgcn_mfma_f32_16x16x32_bf16(pf, vf, accO[nd], 0, 0, 0);
        }
      }
    }
    // ---- epilogue: Y[b][s][h*128+d] = O / l  (bf16)
    #pragma unroll
    for (int r = 0; r < 4; r++) {
      float inv = 1.0f / lst[r];
      int srow = qrow_base + l4 * 4 + r;
      size_t rowbase = ((size_t)(b * 2048 + srow)) * 2048 + h * 128;
      #pragma unroll
      for (int nd = 0; nd < 8; nd++)
        Yg[rowbase + nd * 16 + l15] = f2bf(accO[nd][r] * inv);
    }
  }
}

// ---- GEMM2: out(fp32) = y(bf16) @ w_projT(bf16) + b_proj(fp32)
__global__ __launch_bounds__(256, 3) void gemm_proj(
    const unsigned short* __restrict__ Yin, const unsigned short* __restrict__ WT,
    const float* __restrict__ bias, float* __restrict__ Og) {
  __shared__ unsigned short As[128 * LDK];
  __shared__ unsigned short Bs[128 * LDK];
  int n0 = blockIdx.x * 128, m0 = blockIdx.y * 128;
  floatx4 acc[4][4];
  gemm_tile_mainloop<false>(Yin, WT, 2048, m0, n0, As, Bs, acc);

  const int t = threadIdx.x, lane = t & 63, w = t >> 6;
  const int wm = w >> 1, wn = w & 1;
  const int l15 = lane & 15, l4 = lane >> 4;
  float bv[4];
  #pragma unroll
  for (int ni = 0; ni < 4; ni++)
    bv[ni] = bias[n0 + wn * 64 + ni * 16 + l15];
  #pragma unroll
  for (int mi = 0; mi < 4; mi++)
    #pragma unroll
    for (int ni = 0; ni < 4; ni++)
      #pragma unroll
      for (int r = 0; r < 4; r++)
        Og[(size_t)(m0 + wm * 64 + mi * 16 + l4 * 4 + r) * 2048 +
           n0 + wn * 64 + ni * 16 + l15] = acc[mi][ni][r] + bv[ni];
}

extern "C" void kernel_launch(void* const* d_in, const int* in_sizes, int n_in,
                              void* d_out, int out_size, void* d_ws, size_t ws_size,
                              hipStream_t stream) {
  const float* x      = (const float*)d_in[0]; // [4,2048,2048] fp32
  const float* w_qkv  = (const float*)d_in[1]; // [2048,6144] fp32
  const float* b_qkv  = (const float*)d_in[2]; // [6144] fp32
  const float* w_proj = (const float*)d_in[3]; // [2048,2048] fp32
  const float* b_proj = (const float*)d_in[4]; // [2048] fp32
  float* out = (float*)d_out;                  // [4,2048,2048] fp32 (64 MiB)
  char* ws = (char*)d_ws;

  // d_out doubles as mid-pipeline scratch (fully overwritten by gemm_proj):
  //   Q bf16 [B,H,S,D] at d_out[0,32M), K bf16 at d_out[32M,64M)
  // ws (88 MiB peak):
  //   [0,32M):  Vt bf16 [B,H,D,S]
  //   [32,64M): Y  bf16 [B,S,C]
  //   [64,88M): WqT bf16 [6144,2048], later WpT bf16 [2048,2048] (lifetimes disjoint)
  unsigned short* Q   = (unsigned short*)d_out;
  unsigned short* Kt  = (unsigned short*)((char*)d_out + 33554432);
  unsigned short* Vt  = (unsigned short*)(ws);
  unsigned short* Y   = (unsigned short*)(ws + 33554432);
  unsigned short* WqT = (unsigned short*)(ws + 67108864);
  unsigned short* WpT = (unsigned short*)(ws + 67108864);

  transpose_cvt<<<dim3(192, 64), 256, 0, stream>>>(w_qkv, WqT, 2048, 6144);
  gemm_qkv<<<dim3(48, 64), 256, 0, stream>>>(x, WqT, b_qkv, Q, Kt, Vt);
  attn<<<dim3(1024), 256, 0, stream>>>(Q, Kt, Vt, Y);
  transpose_cvt<<<dim3(64, 64), 256, 0, stream>>>(w_proj, WpT, 2048, 2048);
  gemm_proj<<<dim3(16, 64), 256, 0, stream>>>(Y, WpT, b_proj, out);
}

// Round 5
// 631.428 us; speedup vs baseline: 1.4011x; 1.1533x over previous
//
#include <hip/hip_runtime.h>
#include <hip/hip_bf16.h>

typedef __bf16 bf16x8 __attribute__((ext_vector_type(8)));
typedef float floatx4 __attribute__((ext_vector_type(4)));

#define LDK 72    // attn: 64-wide tiles +8 pad (144B rows)
#define LDD 136   // attn: 128-wide tiles +8 pad (272B rows)

__device__ __forceinline__ unsigned short f2bf(float f) {
  unsigned u = __float_as_uint(f);
  u += 0x7fffu + ((u >> 16) & 1u);   // RNE; inputs finite
  return (unsigned short)(u >> 16);
}

__device__ __forceinline__ void async_copy16(const void* g, void* l) {
  __builtin_amdgcn_global_load_lds(
      (const __attribute__((address_space(1))) void*)g,
      (__attribute__((address_space(3))) void*)l, 16, 0, 0);
}

// ------------- elementwise fp32 -> bf16 (8 elems/thread) -------------
__global__ __launch_bounds__(256) void cvt_bf16(
    const float* __restrict__ in, unsigned short* __restrict__ out) {
  size_t i = ((size_t)blockIdx.x * 256 + threadIdx.x) * 8;
  float4 a0 = *(const float4*)&in[i];
  float4 a1 = *(const float4*)&in[i + 4];
  uint4 d;
  d.x = (unsigned)f2bf(a0.x) | ((unsigned)f2bf(a0.y) << 16);
  d.y = (unsigned)f2bf(a0.z) | ((unsigned)f2bf(a0.w) << 16);
  d.z = (unsigned)f2bf(a1.x) | ((unsigned)f2bf(a1.y) << 16);
  d.w = (unsigned)f2bf(a1.z) | ((unsigned)f2bf(a1.w) << 16);
  *(uint4*)(&out[i]) = d;
}

// ------------- convert+transpose: fp32 [R][Ccol] -> bf16 [Ccol][R] -------------
__global__ __launch_bounds__(256) void transpose_cvt(
    const float* __restrict__ in, unsigned short* __restrict__ out,
    int R, int Ccol) {
  __shared__ unsigned short tile[32][33];
  int c0 = blockIdx.x * 32, r0 = blockIdx.y * 32;
  int tx = threadIdx.x & 31, ty = threadIdx.x >> 5;  // 32 x 8
  #pragma unroll
  for (int i = 0; i < 32; i += 8)
    tile[ty + i][tx] = f2bf(in[(size_t)(r0 + ty + i) * Ccol + c0 + tx]);
  __syncthreads();
  #pragma unroll
  for (int i = 0; i < 32; i += 8)
    out[(size_t)(c0 + ty + i) * R + r0 + tx] = tile[tx][ty + i];
}

// ---- BT-GEMM mainloop (m97 structure): C[128x128] = A[m0..][K] * Bt[n0..][K]^T
// A,Bt bf16. Staging via global_load_lds width=16 into XOR-swizzled LDS
// (LDS slot (r,j) holds global 16B-chunk j^(r&7); rows 128B, no pad).
// Fragment reads land uniform 8 dwords/bank (conflict-free b128).
__device__ __forceinline__ void gemm_bt_mainloop(
    const unsigned short* __restrict__ A, const unsigned short* __restrict__ Bt,
    int K, int m0, int n0,
    unsigned short* As, unsigned short* Bs, floatx4 acc[4][4]) {
  const int t = threadIdx.x;
  const int lane = t & 63, w = t >> 6;
  const int wm = w >> 1, wn = w & 1;
  const int l15 = lane & 15, l4 = lane >> 4;
  const int lrow = lane >> 3, lchunk = lane & 7;   // staging: 8 rows x 8 chunks
  const int gch = lchunk ^ lrow;                   // source chunk for this lane
  const floatx4 zf = {0.f, 0.f, 0.f, 0.f};
  #pragma unroll
  for (int mi = 0; mi < 4; mi++)
    #pragma unroll
    for (int ni = 0; ni < 4; ni++) acc[mi][ni] = zf;

  for (int k0 = 0; k0 < K; k0 += 64) {
    __syncthreads();                 // prior iter's LDS reads done
    #pragma unroll
    for (int i = 0; i < 4; i++) {    // A: 16 regions of 8 rows; wave w -> w*4+i
      int ridx = w * 4 + i;
      int row = ridx * 8 + lrow;
      async_copy16(&A[(size_t)(m0 + row) * K + k0 + gch * 8], &As[ridx * 512]);
    }
    #pragma unroll
    for (int i = 0; i < 4; i++) {
      int ridx = w * 4 + i;
      int row = ridx * 8 + lrow;
      async_copy16(&Bt[(size_t)(n0 + row) * K + k0 + gch * 8], &Bs[ridx * 512]);
    }
    __syncthreads();                 // drains vmcnt -> staged data visible
    #pragma unroll
    for (int kk = 0; kk < 2; kk++) {
      bf16x8 af[4], bfr[4];
      #pragma unroll
      for (int mi = 0; mi < 4; mi++) {
        int row = wm * 64 + mi * 16 + l15;
        af[mi] = *(const bf16x8*)(&As[row * 64 + ((kk * 4 + l4) ^ (l15 & 7)) * 8]);
      }
      #pragma unroll
      for (int ni = 0; ni < 4; ni++) {
        int row = wn * 64 + ni * 16 + l15;
        bfr[ni] = *(const bf16x8*)(&Bs[row * 64 + ((kk * 4 + l4) ^ (l15 & 7)) * 8]);
      }
      #pragma unroll
      for (int mi = 0; mi < 4; mi++)
        #pragma unroll
        for (int ni = 0; ni < 4; ni++)
          acc[mi][ni] = __builtin_amdgcn_mfma_f32_16x16x32_bf16(
              af[mi], bfr[ni], acc[mi][ni], 0, 0, 0);
    }
  }
}

// ---- GEMM1: qkv = xb(bf16) @ w_qkvT(bf16) + b(fp32); Q,K [B,H,S,D], V^T [B,H,D,S]
__global__ __launch_bounds__(256, 3) void gemm_qkv(
    const unsigned short* __restrict__ X, const unsigned short* __restrict__ WT,
    const float* __restrict__ bias,
    unsigned short* __restrict__ Qo, unsigned short* __restrict__ Ko,
    unsigned short* __restrict__ Vto) {
  __shared__ unsigned short As[128 * 64];
  __shared__ unsigned short Bs[128 * 64];
  int n0 = blockIdx.x * 128, m0 = blockIdx.y * 128;
  floatx4 acc[4][4];
  gemm_bt_mainloop(X, WT, 2048, m0, n0, As, Bs, acc);

  const int t = threadIdx.x, lane = t & 63, w = t >> 6;
  const int wm = w >> 1, wn = w & 1;
  const int l15 = lane & 15, l4 = lane >> 4;
  int which = n0 >> 11;            // 0:Q 1:K 2:V  (2048-col boundaries)
  int h = (n0 & 2047) >> 7;        // one head per 128-col block
  int b = m0 >> 11;
  int s0 = m0 & 2047;
  float bv[4];
  #pragma unroll
  for (int ni = 0; ni < 4; ni++)
    bv[ni] = bias[n0 + wn * 64 + ni * 16 + l15];

  if (which < 2) {
    unsigned short* dst = (which == 0) ? Qo : Ko;
    size_t base = (size_t)(b * 16 + h) * 2048;
    #pragma unroll
    for (int mi = 0; mi < 4; mi++)
      #pragma unroll
      for (int ni = 0; ni < 4; ni++) {
        int d = wn * 64 + ni * 16 + l15;
        #pragma unroll
        for (int r = 0; r < 4; r++) {
          int srow = s0 + wm * 64 + mi * 16 + l4 * 4 + r;
          dst[(base + srow) * 128 + d] = f2bf(acc[mi][ni][r] + bv[ni]);
        }
      }
  } else {
    #pragma unroll
    for (int mi = 0; mi < 4; mi++)
      #pragma unroll
      for (int ni = 0; ni < 4; ni++) {
        int d = wn * 64 + ni * 16 + l15;
        int sr = s0 + wm * 64 + mi * 16 + l4 * 4;   // 4 consecutive s rows
        ushort4 v;
        v.x = f2bf(acc[mi][ni][0] + bv[ni]);
        v.y = f2bf(acc[mi][ni][1] + bv[ni]);
        v.z = f2bf(acc[mi][ni][2] + bv[ni]);
        v.w = f2bf(acc[mi][ni][3] + bv[ni]);
        *(ushort4*)(&Vto[((size_t)(b * 16 + h) * 128 + d) * 2048 + sr]) = v;
      }
  }
}

// ---- flash attention: Q,K [B,H,S,D], V^T [B,H,D,S] (bf16) -> Y [B,S,C] (bf16)
__global__ __launch_bounds__(256, 4) void attn(
    const unsigned short* __restrict__ Qg, const unsigned short* __restrict__ Kg,
    const unsigned short* __restrict__ Vtg, unsigned short* __restrict__ Yg) {
  const int S = 2048, Dh = 128;
  const float c1 = 0.08838834764831845f * 1.4426950408889634f;  // scale*log2e
  const float NEG_BIG = -3.0e38f;
  __shared__ __bf16 KsPs[64 * LDD];   // K tile [sk=64][d=128]; P overlay
  __shared__ __bf16 Vs[128 * LDK];    // V^T tile [d=128][sk=64]
  int qtp = blockIdx.x & 15;
  int bh = blockIdx.x >> 4;
  const int t = threadIdx.x, lane = t & 63, w = t >> 6;
  const int l15 = lane & 15, l4 = lane >> 4;
  const unsigned short* Qb = Qg + (size_t)bh * S * Dh;
  const unsigned short* Kb = Kg + (size_t)bh * S * Dh;
  const unsigned short* Vb = Vtg + (size_t)bh * Dh * S;
  __bf16* Pw = &KsPs[w * 16 * LDK];   // per-wave P [16 q][64 sk], stride 72
  int b = bh >> 4, h = bh & 15;
  const floatx4 zf = {0.f, 0.f, 0.f, 0.f};

  #pragma unroll 1
  for (int half = 0; half < 2; half++) {
    int qt = half ? qtp : (31 - qtp);
    int q0 = qt * 64;
    int qrow_base = q0 + w * 16;
    bf16x8 qf[4];
    #pragma unroll
    for (int kk = 0; kk < 4; kk++)
      qf[kk] = *(const bf16x8*)(
          &Qb[(size_t)(qrow_base + l15) * Dh + kk * 32 + l4 * 8]);
    floatx4 accO[8];
    #pragma unroll
    for (int nd = 0; nd < 8; nd++) accO[nd] = zf;
    float mst[4], lst[4];
    #pragma unroll
    for (int r = 0; r < 4; r++) { mst[r] = NEG_BIG; lst[r] = 0.f; }

    int ntiles = qt + 1;
    #pragma unroll 1
    for (int kt = 0; kt < ntiles; kt++) {
      int k0 = kt * 64;
      __syncthreads();
      #pragma unroll
      for (int i = 0; i < 4; i++) {     // stage K: 64 rows x 16 chunks
        int c = t + i * 256;
        *(uint4*)(&KsPs[(c >> 4) * LDD + (c & 15) * 8]) =
            *(const uint4*)(&Kb[(size_t)(k0 + (c >> 4)) * Dh + (c & 15) * 8]);
      }
      #pragma unroll
      for (int i = 0; i < 4; i++) {     // stage V^T: 128 rows x 8 chunks
        int c = t + i * 256;
        *(uint4*)(&Vs[(c >> 3) * LDK + (c & 7) * 8]) =
            *(const uint4*)(&Vb[(size_t)(c >> 3) * S + k0 + (c & 7) * 8]);
      }
      __syncthreads();

      floatx4 sc[4];
      #pragma unroll
      for (int ni = 0; ni < 4; ni++) sc[ni] = zf;
      #pragma unroll
      for (int kk = 0; kk < 4; kk++) {  // QK^T over D=128
        bf16x8 kf[4];
        #pragma unroll
        for (int ni = 0; ni < 4; ni++)
          kf[ni] = *(const bf16x8*)(&KsPs[(ni * 16 + l15) * LDD + kk * 32 + l4 * 8]);
        #pragma unroll
        for (int ni = 0; ni < 4; ni++)
          sc[ni] = __builtin_amdgcn_mfma_f32_16x16x32_bf16(qf[kk], kf[ni], sc[ni], 0, 0, 0);
      }
      __syncthreads();            // all K reads done -> P may overwrite KsPs

      if (kt == qt) {
        #pragma unroll
        for (int ni = 0; ni < 4; ni++)
          #pragma unroll
          for (int r = 0; r < 4; r++)
            if (ni * 16 + l15 > w * 16 + l4 * 4 + r) sc[ni][r] = NEG_BIG;
      }
      float mt[4];
      #pragma unroll
      for (int r = 0; r < 4; r++)
        mt[r] = fmaxf(fmaxf(sc[0][r], sc[1][r]), fmaxf(sc[2][r], sc[3][r]));
      #pragma unroll
      for (int off = 1; off < 16; off <<= 1)
        #pragma unroll
        for (int r = 0; r < 4; r++)
          mt[r] = fmaxf(mt[r], __shfl_xor(mt[r], off, 64));
      float alpha[4], rs[4];
      #pragma unroll
      for (int r = 0; r < 4; r++) {
        float mnew = fmaxf(mst[r], mt[r]);
        alpha[r] = exp2f((mst[r] - mnew) * c1);
        mst[r] = mnew;
        rs[r] = 0.f;
      }
      #pragma unroll
      for (int ni = 0; ni < 4; ni++)
        #pragma unroll
        for (int r = 0; r < 4; r++) {
          float p = exp2f((sc[ni][r] - mst[r]) * c1);
          rs[r] += p;
          Pw[(l4 * 4 + r) * LDK + ni * 16 + l15] = __builtin_bit_cast(__bf16, f2bf(p));
        }
      #pragma unroll
      for (int off = 1; off < 16; off <<= 1)
        #pragma unroll
        for (int r = 0; r < 4; r++)
          rs[r] += __shfl_xor(rs[r], off, 64);
      #pragma unroll
      for (int r = 0; r < 4; r++)
        lst[r] = lst[r] * alpha[r] + rs[r];
      #pragma unroll
      for (int nd = 0; nd < 8; nd++)
        #pragma unroll
        for (int r = 0; r < 4; r++) accO[nd][r] *= alpha[r];
      #pragma unroll
      for (int kk = 0; kk < 2; kk++) {
        bf16x8 pf = *(const bf16x8*)(&Pw[l15 * LDK + kk * 32 + l4 * 8]);
        #pragma unroll
        for (int nd = 0; nd < 8; nd++) {
          bf16x8 vf = *(const bf16x8*)(&Vs[(nd * 16 + l15) * LDK + kk * 32 + l4 * 8]);
          accO[nd] = __builtin_amdgcn_mfma_f32_16x16x32_bf16(pf, vf, accO[nd], 0, 0, 0);
        }
      }
    }
    #pragma unroll
    for (int r = 0; r < 4; r++) {
      float inv = 1.0f / lst[r];
      int srow = qrow_base + l4 * 4 + r;
      size_t rowbase = ((size_t)(b * 2048 + srow)) * 2048 + h * 128;
      #pragma unroll
      for (int nd = 0; nd < 8; nd++)
        Yg[rowbase + nd * 16 + l15] = f2bf(accO[nd][r] * inv);
    }
  }
}

// ---- GEMM2: out(fp32) = y(bf16) @ w_projT(bf16) + b_proj(fp32)
__global__ __launch_bounds__(256, 3) void gemm_proj(
    const unsigned short* __restrict__ Yin, const unsigned short* __restrict__ WT,
    const float* __restrict__ bias, float* __restrict__ Og) {
  __shared__ unsigned short As[128 * 64];
  __shared__ unsigned short Bs[128 * 64];
  int n0 = blockIdx.x * 128, m0 = blockIdx.y * 128;
  floatx4 acc[4][4];
  gemm_bt_mainloop(Yin, WT, 2048, m0, n0, As, Bs, acc);

  const int t = threadIdx.x, lane = t & 63, w = t >> 6;
  const int wm = w >> 1, wn = w & 1;
  const int l15 = lane & 15, l4 = lane >> 4;
  float bv[4];
  #pragma unroll
  for (int ni = 0; ni < 4; ni++)
    bv[ni] = bias[n0 + wn * 64 + ni * 16 + l15];
  #pragma unroll
  for (int mi = 0; mi < 4; mi++)
    #pragma unroll
    for (int ni = 0; ni < 4; ni++)
      #pragma unroll
      for (int r = 0; r < 4; r++)
        Og[(size_t)(m0 + wm * 64 + mi * 16 + l4 * 4 + r) * 2048 +
           n0 + wn * 64 + ni * 16 + l15] = acc[mi][ni][r] + bv[ni];
}

extern "C" void kernel_launch(void* const* d_in, const int* in_sizes, int n_in,
                              void* d_out, int out_size, void* d_ws, size_t ws_size,
                              hipStream_t stream) {
  const float* x      = (const float*)d_in[0]; // [4,2048,2048] fp32
  const float* w_qkv  = (const float*)d_in[1]; // [2048,6144] fp32
  const float* b_qkv  = (const float*)d_in[2]; // [6144] fp32
  const float* w_proj = (const float*)d_in[3]; // [2048,2048] fp32
  const float* b_proj = (const float*)d_in[4]; // [2048] fp32
  float* out = (float*)d_out;                  // [4,2048,2048] fp32 (64 MiB)
  char* ws = (char*)d_ws;

  // d_out doubles as mid-pipeline scratch (fully overwritten by gemm_proj):
  //   Q bf16 at d_out[0,32M), K bf16 at d_out[32M,64M)
  // ws (88 MiB peak), lifetime-shared:
  //   [0,32M):  Vt bf16 [B,H,D,S]
  //   [32,64M): Xbf bf16 (cvt_x -> gemm_qkv), then Y bf16 (attn -> gemm_proj)
  //   [64,88M): WqT bf16 [6144,2048], later WpT bf16 [2048,2048]
  unsigned short* Q   = (unsigned short*)d_out;
  unsigned short* Kt  = (unsigned short*)((char*)d_out + 33554432);
  unsigned short* Vt  = (unsigned short*)(ws);
  unsigned short* Xbf = (unsigned short*)(ws + 33554432);
  unsigned short* Y   = (unsigned short*)(ws + 33554432);
  unsigned short* WqT = (unsigned short*)(ws + 67108864);
  unsigned short* WpT = (unsigned short*)(ws + 67108864);

  cvt_bf16<<<dim3(8192), 256, 0, stream>>>(x, Xbf);                    // 16M elems
  transpose_cvt<<<dim3(192, 64), 256, 0, stream>>>(w_qkv, WqT, 2048, 6144);
  gemm_qkv<<<dim3(48, 64), 256, 0, stream>>>(Xbf, WqT, b_qkv, Q, Kt, Vt);
  attn<<<dim3(1024), 256, 0, stream>>>(Q, Kt, Vt, Y);
  transpose_cvt<<<dim3(64, 64), 256, 0, stream>>>(w_proj, WpT, 2048, 2048);
  gemm_proj<<<dim3(16, 64), 256, 0, stream>>>(Y, WpT, b_proj, out);
}